// Round 1
// baseline (64687.457 us; speedup 1.0000x reference)
//
#include <hip/hip_runtime.h>
#include <stdint.h>

#define N_NODES 20000
#define E_EDGES 640000
#define F1 256
#define HDIM 256
#define G3 768
#define HEADS 8
#define HC 128
#define DH 16
#define NA 8
#define MS 64

typedef _Float16 h2 __attribute__((ext_vector_type(2)));

__device__ __forceinline__ float fdot2(uint32_t a, uint32_t b, float c) {
#if __has_builtin(__builtin_amdgcn_fdot2)
  return __builtin_amdgcn_fdot2(__builtin_bit_cast(h2, a), __builtin_bit_cast(h2, b), c, false);
#else
  h2 x = __builtin_bit_cast(h2, a), y = __builtin_bit_cast(h2, b);
  return c + (float)x[0] * (float)y[0] + (float)x[1] * (float)y[1];
#endif
}

__device__ __forceinline__ float fexp2(float x) { return __builtin_amdgcn_exp2f(x); }
__device__ __forceinline__ float frcp(float x)  { return __builtin_amdgcn_rcpf(x); }
__device__ __forceinline__ float sigm(float x)  { return frcp(1.f + fexp2(-1.44269504f * x)); }
__device__ __forceinline__ float tanh_(float x) {
  x = fminf(20.f, fmaxf(-20.f, x));
  float t = fexp2(2.88539008f * x);
  return (t - 1.f) * frcp(t + 1.f);
}
__device__ __forceinline__ float leaky(float x) { return (x > 0.f) ? x : 0.2f * x; }
// monotone float<->uint encoding for atomic max over signed floats
__device__ __forceinline__ unsigned fenc(float f) {
  unsigned u = __float_as_uint(f);
  return (u & 0x80000000u) ? ~u : (u | 0x80000000u);
}
__device__ __forceinline__ float fdec(unsigned u) {
  return __uint_as_float((u & 0x80000000u) ? (u ^ 0x80000000u) : ~u);
}

// ---------------------------------------------------------------- generic GEMM
// C[M][P] = op(A[M][K] @ B) ; BT0: B[K][P], BT1: B[P][K] (k-contiguous rows)
#define GF_BIAS 1
#define GF_RELU_OUT 2
#define GF_ACC 4
#define GF_RELU_A 8
#define GF_BT 16

template <int FLAGS>
__global__ __launch_bounds__(256) void gemm_k(const float* __restrict__ A,
                                              const float* __restrict__ B,
                                              const float* __restrict__ bias,
                                              float* __restrict__ C,
                                              int M, int K, int P) {
  __shared__ float As[64][68];
  __shared__ float Bs[64][68];
  int colTiles = P >> 6;
  int bx = blockIdx.x % colTiles;
  int by = blockIdx.x / colTiles;
  int row0 = by * 64, col0 = bx * 64;
  int tid = threadIdx.x;
  int tx = tid & 15, ty = tid >> 4;
  float acc[4][4] = {};
  for (int k0 = 0; k0 < K; k0 += 64) {
    {
      int r = tid >> 2, kq = (tid & 3) * 16;
      int gr = row0 + r;
      const float* ap = A + (size_t)gr * K + k0 + kq;
#pragma unroll
      for (int j = 0; j < 4; j++) {
        float4 v = make_float4(0.f, 0.f, 0.f, 0.f);
        if (gr < M) v = *(const float4*)(ap + 4 * j);
        if (FLAGS & GF_RELU_A) {
          v.x = fmaxf(v.x, 0.f); v.y = fmaxf(v.y, 0.f);
          v.z = fmaxf(v.z, 0.f); v.w = fmaxf(v.w, 0.f);
        }
        As[kq + 4 * j + 0][r] = v.x; As[kq + 4 * j + 1][r] = v.y;
        As[kq + 4 * j + 2][r] = v.z; As[kq + 4 * j + 3][r] = v.w;
      }
    }
    if (FLAGS & GF_BT) {
      int n = tid >> 2, kq = (tid & 3) * 16;
      const float* bp = B + (size_t)(col0 + n) * K + k0 + kq;
#pragma unroll
      for (int j = 0; j < 4; j++) {
        float4 v = *(const float4*)(bp + 4 * j);
        Bs[kq + 4 * j + 0][n] = v.x; Bs[kq + 4 * j + 1][n] = v.y;
        Bs[kq + 4 * j + 2][n] = v.z; Bs[kq + 4 * j + 3][n] = v.w;
      }
    } else {
      int kk = tid >> 2, nq = (tid & 3) * 16;
      const float* bp = B + (size_t)(k0 + kk) * P + col0 + nq;
#pragma unroll
      for (int j = 0; j < 4; j++)
        *(float4*)&Bs[kk][nq + 4 * j] = *(const float4*)(bp + 4 * j);
    }
    __syncthreads();
#pragma unroll
    for (int kk = 0; kk < 64; kk++) {
      float4 av = *(const float4*)&As[kk][ty * 4];
      float4 bv = *(const float4*)&Bs[kk][tx * 4];
      float a4[4] = {av.x, av.y, av.z, av.w};
      float b4[4] = {bv.x, bv.y, bv.z, bv.w};
#pragma unroll
      for (int i = 0; i < 4; i++)
#pragma unroll
        for (int j = 0; j < 4; j++) acc[i][j] = fmaf(a4[i], b4[j], acc[i][j]);
    }
    __syncthreads();
  }
#pragma unroll
  for (int i = 0; i < 4; i++) {
    int gr = row0 + ty * 4 + i;
    if (gr >= M) continue;
#pragma unroll
    for (int j = 0; j < 4; j++) {
      int gc = col0 + tx * 4 + j;
      float v = acc[i][j];
      if (FLAGS & GF_BIAS) v += bias[gc];
      if (FLAGS & GF_RELU_OUT) v = fmaxf(v, 0.f);
      size_t o = (size_t)gr * P + gc;
      if (FLAGS & GF_ACC) C[o] += v; else C[o] = v;
    }
  }
}

// ------------------------------------------------- GRU scan weight repack (fp32 -> f16 pairs)
// scan thread t (g=t>>2, c=t&3) owns rows {j,256+j,512+j} for j in {2g,2g+1}, k in [64c,64c+64)
// w[q], q=a*32+p, a in 0..5: row=(a%3)*256+2g+(a/3), k=64c+2p. Layout Wpk[q*512+t] (coalesced).
__global__ __launch_bounds__(256) void prep_w(const float* __restrict__ Whh,
                                              uint32_t* __restrict__ Wpk) {
  int idx = blockIdx.x * 256 + threadIdx.x;
  if (idx >= 192 * 512) return;
  int q = idx >> 9, t = idx & 511;
  int g = t >> 2, c = t & 3;
  int a = q >> 5, p = q & 31;
  int row = (a % 3) * 256 + 2 * g + (a / 3);
  int k = 64 * c + 2 * p;
  h2 v = { (_Float16)Whh[row * 256 + k], (_Float16)Whh[row * 256 + k + 1] };
  Wpk[idx] = __builtin_bit_cast(uint32_t, v);
}

// ---------------------------------------------------------------- GRU sequential scan
// single block, 512 threads; Whh resident in VGPRs as f16 pairs; h ping-pong in LDS (f16 pairs).
__global__ __launch_bounds__(512, 2) void gru_scan(const float* __restrict__ GI,
                                                   const uint32_t* __restrict__ Wpk,
                                                   const float* __restrict__ bhh,
                                                   float* __restrict__ Hout) {
  // chunk layout: 4 chunks x 144B (32 data dwords + 4 pad) -> disjoint banks across c lanes
  __shared__ __align__(16) uint32_t hb[2][4][36];
  int tid = threadIdx.x;
  int g = tid >> 2, c = tid & 3;
  int lane = tid & 63;
  uint32_t w[192];
#pragma unroll
  for (int q = 0; q < 192; q++) w[q] = Wpk[q * 512 + tid];
  for (int i = tid; i < 2 * 4 * 36; i += 512) ((uint32_t*)hb)[i] = 0;
  bool gatel = ((c & 1) == 0);
  int j = 2 * g + (c >> 1);
  float bh_r = 0, bh_z = 0, bh_n = 0, hreg = 0, gr = 0, gz = 0, gn = 0;
  if (gatel) {
    bh_r = bhh[j]; bh_z = bhh[256 + j]; bh_n = bhh[512 + j];
    gr = GI[j]; gz = GI[256 + j]; gn = GI[512 + j];
  }
  __syncthreads();
  int buf = 0;
  const int bl = lane & ~3;
#pragma unroll 1
  for (int t = 0; t < N_NODES; t++) {
    float pgr = 0, pgz = 0, pgn = 0;
    if (gatel) {
      int tn = (t + 1 < N_NODES) ? t + 1 : t;
      const float* gp = GI + (size_t)tn * G3;
      pgr = gp[j]; pgz = gp[256 + j]; pgn = gp[512 + j];
    }
    float a0 = 0, a1 = 0, a2 = 0, a3 = 0, a4 = 0, a5 = 0;
    const uint32_t* hc = &hb[buf][c][0];
    uint4 A0 = *(const uint4*)(hc + 0);
    uint4 B0 = *(const uint4*)(hc + 4);
#pragma unroll
    for (int qq = 0; qq < 4; qq++) {
      uint4 A1 = A0, B1 = B0;
      if (qq < 3) {
        A1 = *(const uint4*)(hc + 8 * (qq + 1));
        B1 = *(const uint4*)(hc + 8 * (qq + 1) + 4);
      }
      uint32_t hp[8] = {A0.x, A0.y, A0.z, A0.w, B0.x, B0.y, B0.z, B0.w};
#pragma unroll
      for (int pp = 0; pp < 8; pp++) {
        int p = 8 * qq + pp;
        a0 = fdot2(w[0 * 32 + p], hp[pp], a0);
        a1 = fdot2(w[1 * 32 + p], hp[pp], a1);
        a2 = fdot2(w[2 * 32 + p], hp[pp], a2);
        a3 = fdot2(w[3 * 32 + p], hp[pp], a3);
        a4 = fdot2(w[4 * 32 + p], hp[pp], a4);
        a5 = fdot2(w[5 * 32 + p], hp[pp], a5);
      }
      A0 = A1; B0 = B1;
    }
    // butterfly over the 4 chunk lanes: slots [r0,z0,n0,r1,z1,n1,0,0]
    float v6 = 0.f, v7 = 0.f;
    float u0, u1, u2, u3;
    {
      float t0 = __shfl_xor(a0, 2, 64), t4 = __shfl_xor(a4, 2, 64);
      u0 = (c & 2) ? a4 + t4 : a0 + t0;
      float t1 = __shfl_xor(a1, 2, 64), t5 = __shfl_xor(a5, 2, 64);
      u1 = (c & 2) ? a5 + t5 : a1 + t1;
      float t2 = __shfl_xor(a2, 2, 64), t6 = __shfl_xor(v6, 2, 64);
      u2 = (c & 2) ? v6 + t6 : a2 + t2;
      float t3 = __shfl_xor(a3, 2, 64), t7 = __shfl_xor(v7, 2, 64);
      u3 = (c & 2) ? v7 + t7 : a3 + t3;
    }
    float f0, f1;
    {
      float t0 = __shfl_xor(u0, 1, 64), t2 = __shfl_xor(u2, 1, 64);
      f0 = (c & 1) ? u2 + t2 : u0 + t0;
      float t1 = __shfl_xor(u1, 1, 64), t3 = __shfl_xor(u3, 1, 64);
      f1 = (c & 1) ? u3 + t3 : u1 + t1;
    }
    // lane0: S0,S1  lane1: S2,S3  lane2: S4,S5
    float ta = __shfl(f0, bl + 1, 64);
    float tb = __shfl(f1, bl + 1, 64);
    if (gatel) {
      float Sr = (c == 0) ? f0 : tb;
      float Sz = (c == 0) ? f1 : f0;
      float Sn = (c == 0) ? ta : f1;
      float r = sigm(gr + bh_r + Sr);
      float z = sigm(gz + bh_z + Sz);
      float n = tanh_(gn + r * (Sn + bh_n));
      float hn = (1.f - z) * n + z * hreg;
      hreg = hn;
      Hout[(size_t)t * HDIM + j] = hn;
      int pj = j >> 1, cc = pj >> 5, half = j & 1;
      ushort* hw = (ushort*)&hb[buf ^ 1][cc][0];
      hw[(pj & 31) * 2 + half] = __builtin_bit_cast(uint16_t, (_Float16)hn);
      gr = pgr; gz = pgz; gn = pgn;
    }
    __syncthreads();
    buf ^= 1;
  }
}

// ---------------------------------------------------------------- GAT pieces
__global__ __launch_bounds__(256) void esed_k(const float* __restrict__ Hg,
                                              const float* __restrict__ a_s,
                                              const float* __restrict__ a_d,
                                              float* __restrict__ es, float* __restrict__ ed) {
  int idx = blockIdx.x * 256 + threadIdx.x;
  if (idx >= N_NODES * HEADS) return;
  int n = idx >> 3, hd = idx & 7;
  const float* hp = Hg + (size_t)n * HC + hd * DH;
  float s = 0, d = 0;
#pragma unroll
  for (int i = 0; i < DH; i++) {
    float h = hp[i];
    s = fmaf(h, a_s[hd * DH + i], s);
    d = fmaf(h, a_d[hd * DH + i], d);
  }
  es[idx] = s; ed[idx] = d;
}

__global__ __launch_bounds__(256) void esmax_k(const float* __restrict__ es,
                                               unsigned* __restrict__ m) {
  int idx = blockIdx.x * 256 + threadIdx.x;
  float v = (idx < N_NODES * HEADS) ? es[idx] : -1e30f;
#pragma unroll
  for (int mask = 32; mask >= 8; mask >>= 1) v = fmaxf(v, __shfl_xor(v, mask, 64));
  if ((threadIdx.x & 63) < 8) atomicMax(&m[threadIdx.x & 7], fenc(v));
}

__global__ __launch_bounds__(256) void attA_k(const int* __restrict__ ei,
                                              const float* __restrict__ es,
                                              const float* __restrict__ ed,
                                              const unsigned* __restrict__ esm,
                                              float* __restrict__ den) {
  int idx = blockIdx.x * 256 + threadIdx.x;
  if (idx >= E_EDGES * HEADS) return;
  int e = idx >> 3, hd = idx & 7;
  int s = ei[e], d = ei[E_EDGES + e];
  float edv = ed[d * 8 + hd];
  float lv = leaky(es[s * 8 + hd] + edv);
  float cb = leaky(fdec(esm[hd]) + edv);  // per-dst shift (exactly cancels in softmax)
  float p = fexp2(1.44269504f * (lv - cb));
  atomicAdd(&den[d * 8 + hd], p);
}

__global__ __launch_bounds__(256) void attB_k(const int* __restrict__ ei,
                                              const float* __restrict__ es,
                                              const float* __restrict__ ed,
                                              const unsigned* __restrict__ esm,
                                              const float* __restrict__ den,
                                              const float* __restrict__ Hg,
                                              float* __restrict__ outb) {
  int idx = blockIdx.x * 256 + threadIdx.x;
  if (idx >= E_EDGES * HEADS) return;
  int e = idx >> 3, hd = idx & 7;
  int s = ei[e], d = ei[E_EDGES + e];
  float edv = ed[d * 8 + hd];
  float lv = leaky(es[s * 8 + hd] + edv);
  float cb = leaky(fdec(esm[hd]) + edv);
  float p = fexp2(1.44269504f * (lv - cb));
  float alpha = p * frcp(den[d * 8 + hd] + 1e-16f);
  const float4* hp = (const float4*)(Hg + (size_t)s * HC + hd * DH);
  float* op = outb + (size_t)d * HC + hd * DH;
#pragma unroll
  for (int q = 0; q < 4; q++) {
    float4 h4 = hp[q];
    atomicAdd(op + 4 * q + 0, alpha * h4.x);
    atomicAdd(op + 4 * q + 1, alpha * h4.y);
    atomicAdd(op + 4 * q + 2, alpha * h4.z);
    atomicAdd(op + 4 * q + 3, alpha * h4.w);
  }
}

__global__ __launch_bounds__(256) void biasrelu_k(const float* __restrict__ in,
                                                  const float* __restrict__ b,
                                                  float* __restrict__ o) {
  int idx = blockIdx.x * 256 + threadIdx.x;
  if (idx >= N_NODES * HC) return;
  o[idx] = fmaxf(in[idx] + b[idx & (HC - 1)], 0.f);
}

// ---------------------------------------------------------------- output heads
__global__ __launch_bounds__(64) void heads_k(const float* __restrict__ xgb,
                                              const float* __restrict__ bg2,
                                              const float* __restrict__ H2,
                                              const float* __restrict__ Wc, const float* __restrict__ bc,
                                              const float* __restrict__ Wmu, const float* __restrict__ bmu,
                                              const float* __restrict__ Wm, const float* __restrict__ bm,
                                              float* __restrict__ out) {
  int n = blockIdx.x, l = threadIdx.x;
  __shared__ float xg[HC];
  __shared__ float xr[HDIM];
  for (int i = l; i < HC; i += 64) xg[i] = xgb[(size_t)n * HC + i] + bg2[i];
  for (int i = l; i < HDIM; i += 64) xr[i] = fmaxf(H2[(size_t)n * HDIM + i], 0.f);
  __syncthreads();
  float acc = bm[l];
#pragma unroll 8
  for (int k = 0; k < HC; k++) acc = fmaf(xg[k], Wm[k * MS + l], acc);
  out[N_NODES + (size_t)n * MS + l] = tanh_(acc);
  if (l < NA) {
    float a = bmu[l];
    for (int k = 0; k < HDIM; k++) a = fmaf(xr[k], Wmu[k * NA + l], a);
    for (int k = 0; k < HC; k++) a = fmaf(xg[k], Wmu[(HDIM + k) * NA + l], a);
    out[N_NODES + (size_t)N_NODES * MS + (size_t)n * NA + l] = tanh_(a);
  }
  if (l == 0) {
    float a = bc[0];
    for (int k = 0; k < HC; k++) a = fmaf(xg[k], Wc[k], a);
    out[n] = sigm(a);
  }
}

// ---------------------------------------------------------------- launch
extern "C" void kernel_launch(void* const* d_in, const int* in_sizes, int n_in,
                              void* d_out, int out_size, void* d_ws, size_t ws_size,
                              hipStream_t stream) {
  const float* state = (const float*)d_in[0];
  const float* message = (const float*)d_in[1];
  const int* ei = (const int*)d_in[2];
  const float* Wfc1 = (const float*)d_in[3]; const float* bfc1 = (const float*)d_in[4];
  const float* Wfc2 = (const float*)d_in[5]; const float* bfc2 = (const float*)d_in[6];
  const float* Wih0 = (const float*)d_in[7]; const float* Whh0 = (const float*)d_in[8];
  const float* bih0 = (const float*)d_in[9]; const float* bhh0 = (const float*)d_in[10];
  const float* Wih1 = (const float*)d_in[11]; const float* Whh1 = (const float*)d_in[12];
  const float* bih1 = (const float*)d_in[13]; const float* bhh1 = (const float*)d_in[14];
  const float* Wg1 = (const float*)d_in[15]; const float* as1 = (const float*)d_in[16];
  const float* ad1 = (const float*)d_in[17]; const float* bg1 = (const float*)d_in[18];
  const float* Wg2 = (const float*)d_in[19]; const float* as2 = (const float*)d_in[20];
  const float* ad2 = (const float*)d_in[21]; const float* bg2 = (const float*)d_in[22];
  const float* Wc = (const float*)d_in[23]; const float* bc = (const float*)d_in[24];
  const float* Wmu = (const float*)d_in[25]; const float* bmu = (const float*)d_in[26];
  const float* Wm = (const float*)d_in[27]; const float* bm = (const float*)d_in[28];

  float* ws = (float*)d_ws;
  // workspace layout (floats); total ~25.7M floats (~103 MB)
  float* GI = ws;                       // [20000 x 768] — dead after scans; GAT reuses region:
  float* HGa = ws;                      //   [20000 x 128] gat h
  float* HGb = ws + 2560000;            //   [20000 x 128] aggregation out
  float* X2  = ws + 5120000;            //   [20000 x 128] relu(gat1+bg1)
  float* ES  = ws + 7680000;            //   [20000 x 8]
  float* ED  = ws + 7840000;            //   [20000 x 8]
  float* DEN = ws + 8000000;            //   [20000 x 8]
  unsigned* ESM = (unsigned*)(ws + 8160000);  // [8]
  float* X  = ws + 15360000;            // [20000 x 256], reused as H1
  float* H2 = ws + 20480000;            // [20000 x 256]
  uint32_t* Wpk = (uint32_t*)(ws + 25600000); // [192*512]
  float* out = (float*)d_out;

  int rt = (N_NODES + 63) / 64;  // 313 row tiles

  // x = relu(state@Wfc1+b) ; x += relu(message@Wfc2+b)
  gemm_k<GF_BIAS | GF_RELU_OUT><<<rt * 4, 256, 0, stream>>>(state, Wfc1, bfc1, X, N_NODES, 64, 256);
  gemm_k<GF_BIAS | GF_RELU_OUT | GF_ACC><<<rt * 4, 256, 0, stream>>>(message, Wfc2, bfc2, X, N_NODES, 64, 256);
  // GRU layer 0
  gemm_k<GF_BIAS | GF_BT><<<rt * 12, 256, 0, stream>>>(X, Wih0, bih0, GI, N_NODES, 256, G3);
  prep_w<<<384, 256, 0, stream>>>(Whh0, Wpk);
  gru_scan<<<1, 512, 0, stream>>>(GI, Wpk, bhh0, X);  // H1 overwrites X (X dead)
  // GRU layer 1
  gemm_k<GF_BIAS | GF_BT><<<rt * 12, 256, 0, stream>>>(X, Wih1, bih1, GI, N_NODES, 256, G3);
  prep_w<<<384, 256, 0, stream>>>(Whh1, Wpk);
  gru_scan<<<1, 512, 0, stream>>>(GI, Wpk, bhh1, H2);
  // GAT layer 1 (input relu(H2) fused into GEMM A-read)
  gemm_k<GF_RELU_A><<<rt * 2, 256, 0, stream>>>(H2, Wg1, nullptr, HGa, N_NODES, 256, HC);
  esed_k<<<625, 256, 0, stream>>>(HGa, as1, ad1, ES, ED);
  hipMemsetAsync(DEN, 0, 160000 * 4, stream);
  hipMemsetAsync(ESM, 0, 8 * 4, stream);
  esmax_k<<<625, 256, 0, stream>>>(ES, ESM);
  attA_k<<<20000, 256, 0, stream>>>(ei, ES, ED, ESM, DEN);
  hipMemsetAsync(HGb, 0, (size_t)2560000 * 4, stream);
  attB_k<<<20000, 256, 0, stream>>>(ei, ES, ED, ESM, DEN, HGa, HGb);
  biasrelu_k<<<10000, 256, 0, stream>>>(HGb, bg1, X2);
  // GAT layer 2
  gemm_k<0><<<rt * 2, 256, 0, stream>>>(X2, Wg2, nullptr, HGa, N_NODES, HC, HC);
  esed_k<<<625, 256, 0, stream>>>(HGa, as2, ad2, ES, ED);
  hipMemsetAsync(DEN, 0, 160000 * 4, stream);
  hipMemsetAsync(ESM, 0, 8 * 4, stream);
  esmax_k<<<625, 256, 0, stream>>>(ES, ESM);
  attA_k<<<20000, 256, 0, stream>>>(ei, ES, ED, ESM, DEN);
  hipMemsetAsync(HGb, 0, (size_t)2560000 * 4, stream);
  attB_k<<<20000, 256, 0, stream>>>(ei, ES, ED, ESM, DEN, HGa, HGb);
  // heads
  heads_k<<<N_NODES, 64, 0, stream>>>(HGb, bg2, H2, Wc, bc, Wmu, bmu, Wm, bm, out);
}

// Round 2
// 58390.991 us; speedup vs baseline: 1.1078x; 1.1078x over previous
//
#include <hip/hip_runtime.h>
#include <stdint.h>

#define N_NODES 20000
#define E_EDGES 640000
#define F1 256
#define HDIM 256
#define G3 768
#define HEADS 8
#define HC 128
#define DH 16
#define NA 8
#define MS 64

typedef _Float16 h2 __attribute__((ext_vector_type(2)));

__device__ __forceinline__ float fdot2(uint32_t a, uint32_t b, float c) {
#if __has_builtin(__builtin_amdgcn_fdot2)
  return __builtin_amdgcn_fdot2(__builtin_bit_cast(h2, a), __builtin_bit_cast(h2, b), c, false);
#else
  h2 x = __builtin_bit_cast(h2, a), y = __builtin_bit_cast(h2, b);
  return c + (float)x[0] * (float)y[0] + (float)x[1] * (float)y[1];
#endif
}

__device__ __forceinline__ float fexp2(float x) { return __builtin_amdgcn_exp2f(x); }
__device__ __forceinline__ float frcp(float x)  { return __builtin_amdgcn_rcpf(x); }
__device__ __forceinline__ float sigm(float x)  { return frcp(1.f + fexp2(-1.44269504f * x)); }
__device__ __forceinline__ float tanh_(float x) {
  x = fminf(20.f, fmaxf(-20.f, x));
  float t = fexp2(2.88539008f * x);
  return (t - 1.f) * frcp(t + 1.f);
}
__device__ __forceinline__ float leaky(float x) { return (x > 0.f) ? x : 0.2f * x; }
__device__ __forceinline__ unsigned fenc(float f) {
  unsigned u = __float_as_uint(f);
  return (u & 0x80000000u) ? ~u : (u | 0x80000000u);
}
__device__ __forceinline__ float fdec(unsigned u) {
  return __uint_as_float((u & 0x80000000u) ? (u ^ 0x80000000u) : ~u);
}

// ---------------------------------------------------------------- generic GEMM
#define GF_BIAS 1
#define GF_RELU_OUT 2
#define GF_ACC 4
#define GF_RELU_A 8
#define GF_BT 16

template <int FLAGS>
__global__ __launch_bounds__(256) void gemm_k(const float* __restrict__ A,
                                              const float* __restrict__ B,
                                              const float* __restrict__ bias,
                                              float* __restrict__ C,
                                              int M, int K, int P) {
  __shared__ float As[64][68];
  __shared__ float Bs[64][68];
  int colTiles = P >> 6;
  int bx = blockIdx.x % colTiles;
  int by = blockIdx.x / colTiles;
  int row0 = by * 64, col0 = bx * 64;
  int tid = threadIdx.x;
  int tx = tid & 15, ty = tid >> 4;
  float acc[4][4] = {};
  for (int k0 = 0; k0 < K; k0 += 64) {
    {
      int r = tid >> 2, kq = (tid & 3) * 16;
      int gr = row0 + r;
      const float* ap = A + (size_t)gr * K + k0 + kq;
#pragma unroll
      for (int j = 0; j < 4; j++) {
        float4 v = make_float4(0.f, 0.f, 0.f, 0.f);
        if (gr < M) v = *(const float4*)(ap + 4 * j);
        if (FLAGS & GF_RELU_A) {
          v.x = fmaxf(v.x, 0.f); v.y = fmaxf(v.y, 0.f);
          v.z = fmaxf(v.z, 0.f); v.w = fmaxf(v.w, 0.f);
        }
        As[kq + 4 * j + 0][r] = v.x; As[kq + 4 * j + 1][r] = v.y;
        As[kq + 4 * j + 2][r] = v.z; As[kq + 4 * j + 3][r] = v.w;
      }
    }
    if (FLAGS & GF_BT) {
      int n = tid >> 2, kq = (tid & 3) * 16;
      const float* bp = B + (size_t)(col0 + n) * K + k0 + kq;
#pragma unroll
      for (int j = 0; j < 4; j++) {
        float4 v = *(const float4*)(bp + 4 * j);
        Bs[kq + 4 * j + 0][n] = v.x; Bs[kq + 4 * j + 1][n] = v.y;
        Bs[kq + 4 * j + 2][n] = v.z; Bs[kq + 4 * j + 3][n] = v.w;
      }
    } else {
      int kk = tid >> 2, nq = (tid & 3) * 16;
      const float* bp = B + (size_t)(k0 + kk) * P + col0 + nq;
#pragma unroll
      for (int j = 0; j < 4; j++)
        *(float4*)&Bs[kk][nq + 4 * j] = *(const float4*)(bp + 4 * j);
    }
    __syncthreads();
#pragma unroll
    for (int kk = 0; kk < 64; kk++) {
      float4 av = *(const float4*)&As[kk][ty * 4];
      float4 bv = *(const float4*)&Bs[kk][tx * 4];
      float a4[4] = {av.x, av.y, av.z, av.w};
      float b4[4] = {bv.x, bv.y, bv.z, bv.w};
#pragma unroll
      for (int i = 0; i < 4; i++)
#pragma unroll
        for (int j = 0; j < 4; j++) acc[i][j] = fmaf(a4[i], b4[j], acc[i][j]);
    }
    __syncthreads();
  }
#pragma unroll
  for (int i = 0; i < 4; i++) {
    int gr = row0 + ty * 4 + i;
    if (gr >= M) continue;
#pragma unroll
    for (int j = 0; j < 4; j++) {
      int gc = col0 + tx * 4 + j;
      float v = acc[i][j];
      if (FLAGS & GF_BIAS) v += bias[gc];
      if (FLAGS & GF_RELU_OUT) v = fmaxf(v, 0.f);
      size_t o = (size_t)gr * P + gc;
      if (FLAGS & GF_ACC) C[o] += v; else C[o] = v;
    }
  }
}

// ------------------------------------------------- GRU weight repack (fp32 -> f16 pairs)
// uint4 layout: Wp4[i*512 + t], i=0..47; component m holds q=4i+m.
// q decomposes a=q>>5 (gate/row-half), p=q&31 (k-pair): row=(a%3)*256+2g+(a/3), k=64c+2p
// with g=t>>2, c=t&3.  Pair p of thread's chunk = (k_sub=p>>2 -> uint4 H_{p>>2}, comp p&3).
__global__ __launch_bounds__(256) void prep_w(const float* __restrict__ Whh,
                                              uint32_t* __restrict__ Wpk) {
  int idx = blockIdx.x * 256 + threadIdx.x;  // dword index
  if (idx >= 48 * 2048) return;
  int i = idx >> 11;
  int rem = idx & 2047;
  int t = rem >> 2, comp = rem & 3;
  int q = 4 * i + comp;
  int g = t >> 2, c = t & 3;
  int a = q >> 5, p = q & 31;
  int row = (a % 3) * 256 + 2 * g + (a / 3);
  int k = 64 * c + 2 * p;
  h2 v = { (_Float16)Whh[row * 256 + k], (_Float16)Whh[row * 256 + k + 1] };
  Wpk[idx] = __builtin_bit_cast(uint32_t, v);
}

// ---------------------------------------------------------------- GRU sequential scan
// 512 threads; Whh in 48 NAMED uint4 VGPRs (192 regs, no array -> no scratch demotion);
// h ping-pong in LDS as f16 pairs, 144B bank-disjoint chunks.
#define WD(i) uint4 W##i = Wp4[(i) * 512 + tid];
#define DOT6(A,B,C,D,E,F, m, hv) \
  a0 = fdot2(A.m, hv, a0); a1 = fdot2(B.m, hv, a1); a2 = fdot2(C.m, hv, a2); \
  a3 = fdot2(D.m, hv, a3); a4 = fdot2(E.m, hv, a4); a5 = fdot2(F.m, hv, a5);
#define DOT4(H, A,B,C,D,E,F) \
  DOT6(A,B,C,D,E,F, x, H.x) DOT6(A,B,C,D,E,F, y, H.y) \
  DOT6(A,B,C,D,E,F, z, H.z) DOT6(A,B,C,D,E,F, w, H.w)

__global__ __launch_bounds__(512, 2) void gru_scan(const float* __restrict__ GI,
                                                   const uint32_t* __restrict__ Wpk,
                                                   const float* __restrict__ bhh,
                                                   float* __restrict__ Hout) {
  __shared__ __align__(16) uint32_t hb[2][4][36];
  int tid = threadIdx.x;
  int g = tid >> 2, c = tid & 3;
  int lane = tid & 63;
  const uint4* Wp4 = (const uint4*)Wpk;
  WD(0)  WD(1)  WD(2)  WD(3)  WD(4)  WD(5)  WD(6)  WD(7)
  WD(8)  WD(9)  WD(10) WD(11) WD(12) WD(13) WD(14) WD(15)
  WD(16) WD(17) WD(18) WD(19) WD(20) WD(21) WD(22) WD(23)
  WD(24) WD(25) WD(26) WD(27) WD(28) WD(29) WD(30) WD(31)
  WD(32) WD(33) WD(34) WD(35) WD(36) WD(37) WD(38) WD(39)
  WD(40) WD(41) WD(42) WD(43) WD(44) WD(45) WD(46) WD(47)
  for (int i = tid; i < 2 * 4 * 36; i += 512) ((uint32_t*)hb)[i] = 0;
  bool gatel = ((c & 1) == 0);
  int j = 2 * g + (c >> 1);
  float bh_r = 0, bh_z = 0, bh_n = 0, hreg = 0, gr = 0, gz = 0, gn = 0;
  if (gatel) {
    bh_r = bhh[j]; bh_z = bhh[256 + j]; bh_n = bhh[512 + j];
    gr = GI[j]; gz = GI[256 + j]; gn = GI[512 + j];
  }
  __syncthreads();
  int buf = 0;
  const int bl = lane & ~3;
#pragma unroll 1
  for (int t = 0; t < N_NODES; t++) {
    float pgr = 0, pgz = 0, pgn = 0;
    if (gatel) {
      int tn = (t + 1 < N_NODES) ? t + 1 : t;
      const float* gp = GI + (size_t)tn * G3;
      pgr = gp[j]; pgz = gp[256 + j]; pgn = gp[512 + j];
    }
    float a0 = 0, a1 = 0, a2 = 0, a3 = 0, a4 = 0, a5 = 0;
    const uint4* hc4 = (const uint4*)(&hb[buf][c][0]);
    uint4 Ha = hc4[0];
    uint4 Hb = hc4[1];
    DOT4(Ha, W0, W8,  W16, W24, W32, W40)  Ha = hc4[2];
    DOT4(Hb, W1, W9,  W17, W25, W33, W41)  Hb = hc4[3];
    DOT4(Ha, W2, W10, W18, W26, W34, W42)  Ha = hc4[4];
    DOT4(Hb, W3, W11, W19, W27, W35, W43)  Hb = hc4[5];
    DOT4(Ha, W4, W12, W20, W28, W36, W44)  Ha = hc4[6];
    DOT4(Hb, W5, W13, W21, W29, W37, W45)  Hb = hc4[7];
    DOT4(Ha, W6, W14, W22, W30, W38, W46)
    DOT4(Hb, W7, W15, W23, W31, W39, W47)
    // butterfly over the 4 chunk lanes: slots [r0,z0,n0,r1,z1,n1,0,0]
    float v6 = 0.f, v7 = 0.f;
    float u0, u1, u2, u3;
    {
      float t0 = __shfl_xor(a0, 2, 64), t4 = __shfl_xor(a4, 2, 64);
      u0 = (c & 2) ? a4 + t4 : a0 + t0;
      float t1 = __shfl_xor(a1, 2, 64), t5 = __shfl_xor(a5, 2, 64);
      u1 = (c & 2) ? a5 + t5 : a1 + t1;
      float t2 = __shfl_xor(a2, 2, 64), t6 = __shfl_xor(v6, 2, 64);
      u2 = (c & 2) ? v6 + t6 : a2 + t2;
      float t3 = __shfl_xor(a3, 2, 64), t7 = __shfl_xor(v7, 2, 64);
      u3 = (c & 2) ? v7 + t7 : a3 + t3;
    }
    float f0, f1;
    {
      float t0 = __shfl_xor(u0, 1, 64), t2 = __shfl_xor(u2, 1, 64);
      f0 = (c & 1) ? u2 + t2 : u0 + t0;
      float t1 = __shfl_xor(u1, 1, 64), t3 = __shfl_xor(u3, 1, 64);
      f1 = (c & 1) ? u3 + t3 : u1 + t1;
    }
    float ta = __shfl(f0, bl + 1, 64);
    float tb = __shfl(f1, bl + 1, 64);
    if (gatel) {
      float Sr = (c == 0) ? f0 : tb;
      float Sz = (c == 0) ? f1 : f0;
      float Sn = (c == 0) ? ta : f1;
      float r = sigm(gr + bh_r + Sr);
      float z = sigm(gz + bh_z + Sz);
      float n = tanh_(gn + r * (Sn + bh_n));
      float hn = (1.f - z) * n + z * hreg;
      hreg = hn;
      Hout[(size_t)t * HDIM + j] = hn;
      int pj = j >> 1, cc = pj >> 5, half = j & 1;
      ushort* hw = (ushort*)&hb[buf ^ 1][cc][0];
      hw[(pj & 31) * 2 + half] = __builtin_bit_cast(uint16_t, (_Float16)hn);
      gr = pgr; gz = pgz; gn = pgn;
    }
    __syncthreads();
    buf ^= 1;
  }
}

// ---------------------------------------------------------------- GAT pieces
__global__ __launch_bounds__(256) void esed_k(const float* __restrict__ Hg,
                                              const float* __restrict__ a_s,
                                              const float* __restrict__ a_d,
                                              float* __restrict__ es, float* __restrict__ ed) {
  int idx = blockIdx.x * 256 + threadIdx.x;
  if (idx >= N_NODES * HEADS) return;
  int n = idx >> 3, hd = idx & 7;
  const float* hp = Hg + (size_t)n * HC + hd * DH;
  float s = 0, d = 0;
#pragma unroll
  for (int i = 0; i < DH; i++) {
    float h = hp[i];
    s = fmaf(h, a_s[hd * DH + i], s);
    d = fmaf(h, a_d[hd * DH + i], d);
  }
  es[idx] = s; ed[idx] = d;
}

__global__ __launch_bounds__(256) void esmax_k(const float* __restrict__ es,
                                               unsigned* __restrict__ m) {
  int idx = blockIdx.x * 256 + threadIdx.x;
  float v = (idx < N_NODES * HEADS) ? es[idx] : -1e30f;
#pragma unroll
  for (int mask = 32; mask >= 8; mask >>= 1) v = fmaxf(v, __shfl_xor(v, mask, 64));
  if ((threadIdx.x & 63) < 8) atomicMax(&m[threadIdx.x & 7], fenc(v));
}

// ---------------------------------------------------------------- CSR build
__global__ __launch_bounds__(256) void deg_k(const int* __restrict__ ei, int* __restrict__ deg) {
  int e = blockIdx.x * 256 + threadIdx.x;
  if (e >= E_EDGES) return;
  atomicAdd(&deg[ei[E_EDGES + e]], 1);
}

__global__ __launch_bounds__(1024) void scan_k(const int* __restrict__ deg, int* __restrict__ off) {
  __shared__ int wsum[16];
  __shared__ int carry;
  int tid = threadIdx.x, lane = tid & 63, wv = tid >> 6;
  if (tid == 0) carry = 0;
  __syncthreads();
  for (int base = 0; base < N_NODES; base += 1024) {
    int i = base + tid;
    int v = (i < N_NODES) ? deg[i] : 0;
    int s = v;
#pragma unroll
    for (int d = 1; d < 64; d <<= 1) {
      int t = __shfl_up(s, d, 64);
      if (lane >= d) s += t;
    }
    if (lane == 63) wsum[wv] = s;
    __syncthreads();
    if (wv == 0 && lane < 16) {
      int t = wsum[lane];
#pragma unroll
      for (int d = 1; d < 16; d <<= 1) {
        int u = __shfl_up(t, d, 64);
        if (lane >= d) t += u;
      }
      wsum[lane] = t;
    }
    __syncthreads();
    int prev = (wv > 0) ? wsum[wv - 1] : 0;
    int excl = carry + prev + s - v;
    if (i < N_NODES) off[i] = excl;
    int total = wsum[15];
    __syncthreads();
    if (tid == 0) carry += total;
    __syncthreads();
  }
  if (tid == 0) off[N_NODES] = carry;
}

__global__ __launch_bounds__(256) void scatter_k(const int* __restrict__ ei,
                                                 const int* __restrict__ off,
                                                 int* __restrict__ cnt,
                                                 int* __restrict__ csr_src) {
  int e = blockIdx.x * 256 + threadIdx.x;
  if (e >= E_EDGES) return;
  int d = ei[E_EDGES + e];
  int pos = off[d] + atomicAdd(&cnt[d], 1);
  csr_src[pos] = ei[e];
}

// ---------------------------------------------------------------- GAT gather (1 wave / dst)
template <int RELU>
__global__ __launch_bounds__(256) void gather_k(const int* __restrict__ off,
                                                const int* __restrict__ csr_src,
                                                const float* __restrict__ es,
                                                const float* __restrict__ ed,
                                                const unsigned* __restrict__ esm,
                                                const float* __restrict__ Hg,
                                                const float* __restrict__ bias,
                                                float* __restrict__ out) {
  int wv = threadIdx.x >> 6, lane = threadIdx.x & 63;
  int d = blockIdx.x * 4 + wv;
  if (d >= N_NODES) return;
  int hd0 = lane >> 4, hd1 = 4 + (lane >> 4);
  float ed0 = ed[d * 8 + hd0], ed1 = ed[d * 8 + hd1];
  float cb0 = leaky(fdec(esm[hd0]) + ed0);
  float cb1 = leaky(fdec(esm[hd1]) + ed1);
  int e0 = off[d], e1 = off[d + 1];
  float acc0 = 0, acc1 = 0, den0 = 0, den1 = 0;
  for (int i = e0; i < e1; i++) {
    int s = csr_src[i];
    float p0 = fexp2(1.44269504f * (leaky(es[s * 8 + hd0] + ed0) - cb0));
    float p1 = fexp2(1.44269504f * (leaky(es[s * 8 + hd1] + ed1) - cb1));
    float h0 = Hg[(size_t)s * HC + lane];
    float h1 = Hg[(size_t)s * HC + 64 + lane];
    acc0 = fmaf(p0, h0, acc0); acc1 = fmaf(p1, h1, acc1);
    den0 += p0; den1 += p1;
  }
  float o0 = acc0 * frcp(den0 + 1e-16f);
  float o1 = acc1 * frcp(den1 + 1e-16f);
  if (RELU) {
    o0 = fmaxf(o0 + bias[lane], 0.f);
    o1 = fmaxf(o1 + bias[64 + lane], 0.f);
  }
  out[(size_t)d * HC + lane] = o0;
  out[(size_t)d * HC + 64 + lane] = o1;
}

// ---------------------------------------------------------------- output heads
__global__ __launch_bounds__(64) void heads_k(const float* __restrict__ xgb,
                                              const float* __restrict__ bg2,
                                              const float* __restrict__ H2,
                                              const float* __restrict__ Wc, const float* __restrict__ bc,
                                              const float* __restrict__ Wmu, const float* __restrict__ bmu,
                                              const float* __restrict__ Wm, const float* __restrict__ bm,
                                              float* __restrict__ out) {
  int n = blockIdx.x, l = threadIdx.x;
  __shared__ float xg[HC];
  __shared__ float xr[HDIM];
  for (int i = l; i < HC; i += 64) xg[i] = xgb[(size_t)n * HC + i] + bg2[i];
  for (int i = l; i < HDIM; i += 64) xr[i] = fmaxf(H2[(size_t)n * HDIM + i], 0.f);
  __syncthreads();
  float acc = bm[l];
#pragma unroll 8
  for (int k = 0; k < HC; k++) acc = fmaf(xg[k], Wm[k * MS + l], acc);
  out[N_NODES + (size_t)n * MS + l] = tanh_(acc);
  if (l < NA) {
    float a = bmu[l];
    for (int k = 0; k < HDIM; k++) a = fmaf(xr[k], Wmu[k * NA + l], a);
    for (int k = 0; k < HC; k++) a = fmaf(xg[k], Wmu[(HDIM + k) * NA + l], a);
    out[N_NODES + (size_t)N_NODES * MS + (size_t)n * NA + l] = tanh_(a);
  }
  if (l == 0) {
    float a = bc[0];
    for (int k = 0; k < HC; k++) a = fmaf(xg[k], Wc[k], a);
    out[n] = sigm(a);
  }
}

// ---------------------------------------------------------------- launch
extern "C" void kernel_launch(void* const* d_in, const int* in_sizes, int n_in,
                              void* d_out, int out_size, void* d_ws, size_t ws_size,
                              hipStream_t stream) {
  const float* state = (const float*)d_in[0];
  const float* message = (const float*)d_in[1];
  const int* ei = (const int*)d_in[2];
  const float* Wfc1 = (const float*)d_in[3]; const float* bfc1 = (const float*)d_in[4];
  const float* Wfc2 = (const float*)d_in[5]; const float* bfc2 = (const float*)d_in[6];
  const float* Wih0 = (const float*)d_in[7]; const float* Whh0 = (const float*)d_in[8];
  const float* bih0 = (const float*)d_in[9]; const float* bhh0 = (const float*)d_in[10];
  const float* Wih1 = (const float*)d_in[11]; const float* Whh1 = (const float*)d_in[12];
  const float* bih1 = (const float*)d_in[13]; const float* bhh1 = (const float*)d_in[14];
  const float* Wg1 = (const float*)d_in[15]; const float* as1 = (const float*)d_in[16];
  const float* ad1 = (const float*)d_in[17]; const float* bg1 = (const float*)d_in[18];
  const float* Wg2 = (const float*)d_in[19]; const float* as2 = (const float*)d_in[20];
  const float* ad2 = (const float*)d_in[21]; const float* bg2 = (const float*)d_in[22];
  const float* Wc = (const float*)d_in[23]; const float* bc = (const float*)d_in[24];
  const float* Wmu = (const float*)d_in[25]; const float* bmu = (const float*)d_in[26];
  const float* Wm = (const float*)d_in[27]; const float* bm = (const float*)d_in[28];

  float* ws = (float*)d_ws;
  // workspace layout (floats); footprint identical to R1 (~103 MB)
  float* GI = ws;                       // [20000 x 768]; dead after scans, region reused:
  float* HGa = ws;                      //   [20000 x 128] gat h
  float* HGb = ws + 2560000;            //   [20000 x 128] aggregation out (layer2)
  float* X2  = ws + 5120000;            //   [20000 x 128] relu(gat1+bg1)
  float* ES  = ws + 7680000;            //   [20000 x 8]
  float* ED  = ws + 7840000;            //   [20000 x 8]
  unsigned* ESM = (unsigned*)(ws + 8160000);  // [8]
  int* DEG = (int*)(ws + 8200000);      //   [20000]
  int* OFF = (int*)(ws + 8230000);      //   [20001]
  int* CNT = (int*)(ws + 8260000);      //   [20000]
  int* CSR = (int*)(ws + 8300000);      //   [640000]
  float* X  = ws + 15360000;            // [20000 x 256], reused as H1
  float* H2 = ws + 20480000;            // [20000 x 256]
  uint32_t* Wpk = (uint32_t*)(ws + 25600000); // [48*512 uint4 = 98304 dwords]
  float* out = (float*)d_out;

  int rt = (N_NODES + 63) / 64;  // 313 row tiles

  // x = relu(state@Wfc1+b) + relu(message@Wfc2+b)
  gemm_k<GF_BIAS | GF_RELU_OUT><<<rt * 4, 256, 0, stream>>>(state, Wfc1, bfc1, X, N_NODES, 64, 256);
  gemm_k<GF_BIAS | GF_RELU_OUT | GF_ACC><<<rt * 4, 256, 0, stream>>>(message, Wfc2, bfc2, X, N_NODES, 64, 256);
  // GRU layer 0
  gemm_k<GF_BIAS | GF_BT><<<rt * 12, 256, 0, stream>>>(X, Wih0, bih0, GI, N_NODES, 256, G3);
  prep_w<<<384, 256, 0, stream>>>(Whh0, Wpk);
  gru_scan<<<1, 512, 0, stream>>>(GI, Wpk, bhh0, X);  // H1 overwrites X
  // GRU layer 1
  gemm_k<GF_BIAS | GF_BT><<<rt * 12, 256, 0, stream>>>(X, Wih1, bih1, GI, N_NODES, 256, G3);
  prep_w<<<384, 256, 0, stream>>>(Whh1, Wpk);
  gru_scan<<<1, 512, 0, stream>>>(GI, Wpk, bhh1, H2);
  // CSR build (GI dead now; CSR lives in its tail)
  hipMemsetAsync(DEG, 0, N_NODES * 4, stream);
  hipMemsetAsync(CNT, 0, N_NODES * 4, stream);
  deg_k<<<2500, 256, 0, stream>>>(ei, DEG);
  scan_k<<<1, 1024, 0, stream>>>(DEG, OFF);
  scatter_k<<<2500, 256, 0, stream>>>(ei, OFF, CNT, CSR);
  // GAT layer 1 (relu(H2) fused into GEMM A-read)
  gemm_k<GF_RELU_A><<<rt * 2, 256, 0, stream>>>(H2, Wg1, nullptr, HGa, N_NODES, 256, HC);
  esed_k<<<625, 256, 0, stream>>>(HGa, as1, ad1, ES, ED);
  hipMemsetAsync(ESM, 0, 8 * 4, stream);
  esmax_k<<<625, 256, 0, stream>>>(ES, ESM);
  gather_k<1><<<5000, 256, 0, stream>>>(OFF, CSR, ES, ED, ESM, HGa, bg1, X2);
  // GAT layer 2
  gemm_k<0><<<rt * 2, 256, 0, stream>>>(X2, Wg2, nullptr, HGa, N_NODES, HC, HC);
  esed_k<<<625, 256, 0, stream>>>(HGa, as2, ad2, ES, ED);
  hipMemsetAsync(ESM, 0, 8 * 4, stream);
  esmax_k<<<625, 256, 0, stream>>>(ES, ESM);
  gather_k<0><<<5000, 256, 0, stream>>>(OFF, CSR, ES, ED, ESM, HGa, nullptr, HGb);
  // heads
  heads_k<<<N_NODES, 64, 0, stream>>>(HGb, bg2, H2, Wc, bc, Wmu, bmu, Wm, bm, out);
}

// Round 3
// 51926.642 us; speedup vs baseline: 1.2457x; 1.1245x over previous
//
#include <hip/hip_runtime.h>
#include <stdint.h>

#define N_NODES 20000
#define E_EDGES 640000
#define F1 256
#define HDIM 256
#define G3 768
#define HEADS 8
#define HC 128
#define DH 16
#define NA 8
#define MS 64

typedef _Float16 h2 __attribute__((ext_vector_type(2)));

__device__ __forceinline__ float fdot2(uint32_t a, uint32_t b, float c) {
#if __has_builtin(__builtin_amdgcn_fdot2)
  return __builtin_amdgcn_fdot2(__builtin_bit_cast(h2, a), __builtin_bit_cast(h2, b), c, false);
#else
  h2 x = __builtin_bit_cast(h2, a), y = __builtin_bit_cast(h2, b);
  return c + (float)x[0] * (float)y[0] + (float)x[1] * (float)y[1];
#endif
}

__device__ __forceinline__ float fexp2(float x) { return __builtin_amdgcn_exp2f(x); }
__device__ __forceinline__ float frcp(float x)  { return __builtin_amdgcn_rcpf(x); }
__device__ __forceinline__ float sigm(float x)  { return frcp(1.f + fexp2(-1.44269504f * x)); }
__device__ __forceinline__ float tanh_(float x) {
  x = fminf(20.f, fmaxf(-20.f, x));
  float t = fexp2(2.88539008f * x);
  return (t - 1.f) * frcp(t + 1.f);
}
__device__ __forceinline__ float leaky(float x) { return (x > 0.f) ? x : 0.2f * x; }
__device__ __forceinline__ unsigned fenc(float f) {
  unsigned u = __float_as_uint(f);
  return (u & 0x80000000u) ? ~u : (u | 0x80000000u);
}
__device__ __forceinline__ float fdec(unsigned u) {
  return __uint_as_float((u & 0x80000000u) ? (u ^ 0x80000000u) : ~u);
}

// ---------------------------------------------------------------- generic GEMM
#define GF_BIAS 1
#define GF_RELU_OUT 2
#define GF_ACC 4
#define GF_RELU_A 8
#define GF_BT 16

template <int FLAGS>
__global__ __launch_bounds__(256) void gemm_k(const float* __restrict__ A,
                                              const float* __restrict__ B,
                                              const float* __restrict__ bias,
                                              float* __restrict__ C,
                                              int M, int K, int P) {
  __shared__ float As[64][68];
  __shared__ float Bs[64][68];
  int colTiles = P >> 6;
  int bx = blockIdx.x % colTiles;
  int by = blockIdx.x / colTiles;
  int row0 = by * 64, col0 = bx * 64;
  int tid = threadIdx.x;
  int tx = tid & 15, ty = tid >> 4;
  float acc[4][4] = {};
  for (int k0 = 0; k0 < K; k0 += 64) {
    {
      int r = tid >> 2, kq = (tid & 3) * 16;
      int gr = row0 + r;
      const float* ap = A + (size_t)gr * K + k0 + kq;
#pragma unroll
      for (int j = 0; j < 4; j++) {
        float4 v = make_float4(0.f, 0.f, 0.f, 0.f);
        if (gr < M) v = *(const float4*)(ap + 4 * j);
        if (FLAGS & GF_RELU_A) {
          v.x = fmaxf(v.x, 0.f); v.y = fmaxf(v.y, 0.f);
          v.z = fmaxf(v.z, 0.f); v.w = fmaxf(v.w, 0.f);
        }
        As[kq + 4 * j + 0][r] = v.x; As[kq + 4 * j + 1][r] = v.y;
        As[kq + 4 * j + 2][r] = v.z; As[kq + 4 * j + 3][r] = v.w;
      }
    }
    if (FLAGS & GF_BT) {
      int n = tid >> 2, kq = (tid & 3) * 16;
      const float* bp = B + (size_t)(col0 + n) * K + k0 + kq;
#pragma unroll
      for (int j = 0; j < 4; j++) {
        float4 v = *(const float4*)(bp + 4 * j);
        Bs[kq + 4 * j + 0][n] = v.x; Bs[kq + 4 * j + 1][n] = v.y;
        Bs[kq + 4 * j + 2][n] = v.z; Bs[kq + 4 * j + 3][n] = v.w;
      }
    } else {
      int kk = tid >> 2, nq = (tid & 3) * 16;
      const float* bp = B + (size_t)(k0 + kk) * P + col0 + nq;
#pragma unroll
      for (int j = 0; j < 4; j++)
        *(float4*)&Bs[kk][nq + 4 * j] = *(const float4*)(bp + 4 * j);
    }
    __syncthreads();
#pragma unroll
    for (int kk = 0; kk < 64; kk++) {
      float4 av = *(const float4*)&As[kk][ty * 4];
      float4 bv = *(const float4*)&Bs[kk][tx * 4];
      float a4[4] = {av.x, av.y, av.z, av.w};
      float b4[4] = {bv.x, bv.y, bv.z, bv.w};
#pragma unroll
      for (int i = 0; i < 4; i++)
#pragma unroll
        for (int j = 0; j < 4; j++) acc[i][j] = fmaf(a4[i], b4[j], acc[i][j]);
    }
    __syncthreads();
  }
#pragma unroll
  for (int i = 0; i < 4; i++) {
    int gr = row0 + ty * 4 + i;
    if (gr >= M) continue;
#pragma unroll
    for (int j = 0; j < 4; j++) {
      int gc = col0 + tx * 4 + j;
      float v = acc[i][j];
      if (FLAGS & GF_BIAS) v += bias[gc];
      if (FLAGS & GF_RELU_OUT) v = fmaxf(v, 0.f);
      size_t o = (size_t)gr * P + gc;
      if (FLAGS & GF_ACC) C[o] += v; else C[o] = v;
    }
  }
}

// ------------------------------------------------- GRU weight repack (fp32 -> f16 pairs)
__global__ __launch_bounds__(256) void prep_w(const float* __restrict__ Whh,
                                              uint32_t* __restrict__ Wpk) {
  int idx = blockIdx.x * 256 + threadIdx.x;  // dword index
  if (idx >= 48 * 2048) return;
  int i = idx >> 11;
  int rem = idx & 2047;
  int t = rem >> 2, comp = rem & 3;
  int q = 4 * i + comp;
  int g = t >> 2, c = t & 3;
  int a = q >> 5, p = q & 31;
  int row = (a % 3) * 256 + 2 * g + (a / 3);
  int k = 64 * c + 2 * p;
  h2 v = { (_Float16)Whh[row * 256 + k], (_Float16)Whh[row * 256 + k + 1] };
  Wpk[idx] = __builtin_bit_cast(uint32_t, v);
}

// ---------------------------------------------------------------- GRU sequential scan
// 512 threads; Whh held in 48 named uint4 VGPRs, PINNED via opaque asm so the
// compiler cannot sink the loads back into the loop (R2 failure mode: it re-loaded
// from global every step -> 30 GB FETCH). h ping-pong in LDS as f16 pairs.
#define WD(i) uint4 W##i = Wp4[(i) * 512 + tid];
#define PIN(i) asm volatile("" : "+v"(W##i.x), "+v"(W##i.y), "+v"(W##i.z), "+v"(W##i.w));
#define DOT6(A,B,C,D,E,F, m, hv) \
  a0 = fdot2(A.m, hv, a0); a1 = fdot2(B.m, hv, a1); a2 = fdot2(C.m, hv, a2); \
  a3 = fdot2(D.m, hv, a3); a4 = fdot2(E.m, hv, a4); a5 = fdot2(F.m, hv, a5);
#define DOT4(H, A,B,C,D,E,F) \
  DOT6(A,B,C,D,E,F, x, H.x) DOT6(A,B,C,D,E,F, y, H.y) \
  DOT6(A,B,C,D,E,F, z, H.z) DOT6(A,B,C,D,E,F, w, H.w)

__global__ __launch_bounds__(512, 2) void gru_scan(const float* __restrict__ GI,
                                                   const uint32_t* __restrict__ Wpk,
                                                   const float* __restrict__ bhh,
                                                   float* __restrict__ Hout) {
  __shared__ __align__(16) uint32_t hb[2][4][36];
  int tid = threadIdx.x;
  int g = tid >> 2, c = tid & 3;
  int lane = tid & 63;
  const uint4* Wp4 = (const uint4*)Wpk;
  WD(0)  WD(1)  WD(2)  WD(3)  WD(4)  WD(5)  WD(6)  WD(7)
  WD(8)  WD(9)  WD(10) WD(11) WD(12) WD(13) WD(14) WD(15)
  WD(16) WD(17) WD(18) WD(19) WD(20) WD(21) WD(22) WD(23)
  WD(24) WD(25) WD(26) WD(27) WD(28) WD(29) WD(30) WD(31)
  WD(32) WD(33) WD(34) WD(35) WD(36) WD(37) WD(38) WD(39)
  WD(40) WD(41) WD(42) WD(43) WD(44) WD(45) WD(46) WD(47)
  PIN(0)  PIN(1)  PIN(2)  PIN(3)  PIN(4)  PIN(5)  PIN(6)  PIN(7)
  PIN(8)  PIN(9)  PIN(10) PIN(11) PIN(12) PIN(13) PIN(14) PIN(15)
  PIN(16) PIN(17) PIN(18) PIN(19) PIN(20) PIN(21) PIN(22) PIN(23)
  PIN(24) PIN(25) PIN(26) PIN(27) PIN(28) PIN(29) PIN(30) PIN(31)
  PIN(32) PIN(33) PIN(34) PIN(35) PIN(36) PIN(37) PIN(38) PIN(39)
  PIN(40) PIN(41) PIN(42) PIN(43) PIN(44) PIN(45) PIN(46) PIN(47)
  for (int i = tid; i < 2 * 4 * 36; i += 512) ((uint32_t*)hb)[i] = 0;
  bool gatel = ((c & 1) == 0);
  int j = 2 * g + (c >> 1);
  float bh_r = 0, bh_z = 0, bh_n = 0, hreg = 0, gr = 0, gz = 0, gn = 0;
  if (gatel) {
    bh_r = bhh[j]; bh_z = bhh[256 + j]; bh_n = bhh[512 + j];
    gr = GI[j]; gz = GI[256 + j]; gn = GI[512 + j];
  }
  __syncthreads();
  int buf = 0;
  const int bl = lane & ~3;
#pragma unroll 1
  for (int t = 0; t < N_NODES; t++) {
    float pgr = 0, pgz = 0, pgn = 0;
    if (gatel) {
      int tn = (t + 1 < N_NODES) ? t + 1 : t;
      const float* gp = GI + (size_t)tn * G3;
      pgr = gp[j]; pgz = gp[256 + j]; pgn = gp[512 + j];
    }
    float a0 = 0, a1 = 0, a2 = 0, a3 = 0, a4 = 0, a5 = 0;
    const uint4* hc4 = (const uint4*)(&hb[buf][c][0]);
    uint4 Ha = hc4[0];
    uint4 Hb = hc4[1];
    DOT4(Ha, W0, W8,  W16, W24, W32, W40)  Ha = hc4[2];
    DOT4(Hb, W1, W9,  W17, W25, W33, W41)  Hb = hc4[3];
    DOT4(Ha, W2, W10, W18, W26, W34, W42)  Ha = hc4[4];
    DOT4(Hb, W3, W11, W19, W27, W35, W43)  Hb = hc4[5];
    DOT4(Ha, W4, W12, W20, W28, W36, W44)  Ha = hc4[6];
    DOT4(Hb, W5, W13, W21, W29, W37, W45)  Hb = hc4[7];
    DOT4(Ha, W6, W14, W22, W30, W38, W46)
    DOT4(Hb, W7, W15, W23, W31, W39, W47)
    // butterfly over the 4 chunk lanes: slots [r0,z0,n0,r1,z1,n1,0,0]
    float v6 = 0.f, v7 = 0.f;
    float u0, u1, u2, u3;
    {
      float t0 = __shfl_xor(a0, 2, 64), t4 = __shfl_xor(a4, 2, 64);
      u0 = (c & 2) ? a4 + t4 : a0 + t0;
      float t1 = __shfl_xor(a1, 2, 64), t5 = __shfl_xor(a5, 2, 64);
      u1 = (c & 2) ? a5 + t5 : a1 + t1;
      float t2 = __shfl_xor(a2, 2, 64), t6 = __shfl_xor(v6, 2, 64);
      u2 = (c & 2) ? v6 + t6 : a2 + t2;
      float t3 = __shfl_xor(a3, 2, 64), t7 = __shfl_xor(v7, 2, 64);
      u3 = (c & 2) ? v7 + t7 : a3 + t3;
    }
    float f0, f1;
    {
      float t0 = __shfl_xor(u0, 1, 64), t2 = __shfl_xor(u2, 1, 64);
      f0 = (c & 1) ? u2 + t2 : u0 + t0;
      float t1 = __shfl_xor(u1, 1, 64), t3 = __shfl_xor(u3, 1, 64);
      f1 = (c & 1) ? u3 + t3 : u1 + t1;
    }
    float ta = __shfl(f0, bl + 1, 64);
    float tb = __shfl(f1, bl + 1, 64);
    if (gatel) {
      float Sr = (c == 0) ? f0 : tb;
      float Sz = (c == 0) ? f1 : f0;
      float Sn = (c == 0) ? ta : f1;
      float r = sigm(gr + bh_r + Sr);
      float z = sigm(gz + bh_z + Sz);
      float n = tanh_(gn + r * (Sn + bh_n));
      float hn = (1.f - z) * n + z * hreg;
      hreg = hn;
      Hout[(size_t)t * HDIM + j] = hn;
      int pj = j >> 1, cc = pj >> 5, half = j & 1;
      ushort* hw = (ushort*)&hb[buf ^ 1][cc][0];
      hw[(pj & 31) * 2 + half] = __builtin_bit_cast(uint16_t, (_Float16)hn);
      gr = pgr; gz = pgz; gn = pgn;
    }
    __syncthreads();
    buf ^= 1;
  }
}

// ---------------------------------------------------------------- GAT pieces
__global__ __launch_bounds__(256) void esed_k(const float* __restrict__ Hg,
                                              const float* __restrict__ a_s,
                                              const float* __restrict__ a_d,
                                              float* __restrict__ es, float* __restrict__ ed) {
  int idx = blockIdx.x * 256 + threadIdx.x;
  if (idx >= N_NODES * HEADS) return;
  int n = idx >> 3, hd = idx & 7;
  const float* hp = Hg + (size_t)n * HC + hd * DH;
  float s = 0, d = 0;
#pragma unroll
  for (int i = 0; i < DH; i++) {
    float h = hp[i];
    s = fmaf(h, a_s[hd * DH + i], s);
    d = fmaf(h, a_d[hd * DH + i], d);
  }
  es[idx] = s; ed[idx] = d;
}

__global__ __launch_bounds__(256) void esmax_k(const float* __restrict__ es,
                                               unsigned* __restrict__ m) {
  int idx = blockIdx.x * 256 + threadIdx.x;
  float v = (idx < N_NODES * HEADS) ? es[idx] : -1e30f;
#pragma unroll
  for (int mask = 32; mask >= 8; mask >>= 1) v = fmaxf(v, __shfl_xor(v, mask, 64));
  if ((threadIdx.x & 63) < 8) atomicMax(&m[threadIdx.x & 7], fenc(v));
}

// ---------------------------------------------------------------- CSR build
__global__ __launch_bounds__(256) void deg_k(const int* __restrict__ ei, int* __restrict__ deg) {
  int e = blockIdx.x * 256 + threadIdx.x;
  if (e >= E_EDGES) return;
  atomicAdd(&deg[ei[E_EDGES + e]], 1);
}

__global__ __launch_bounds__(1024) void scan_k(const int* __restrict__ deg, int* __restrict__ off) {
  __shared__ int wsum[16];
  __shared__ int carry;
  int tid = threadIdx.x, lane = tid & 63, wv = tid >> 6;
  if (tid == 0) carry = 0;
  __syncthreads();
  for (int base = 0; base < N_NODES; base += 1024) {
    int i = base + tid;
    int v = (i < N_NODES) ? deg[i] : 0;
    int s = v;
#pragma unroll
    for (int d = 1; d < 64; d <<= 1) {
      int t = __shfl_up(s, d, 64);
      if (lane >= d) s += t;
    }
    if (lane == 63) wsum[wv] = s;
    __syncthreads();
    if (wv == 0 && lane < 16) {
      int t = wsum[lane];
#pragma unroll
      for (int d = 1; d < 16; d <<= 1) {
        int u = __shfl_up(t, d, 64);
        if (lane >= d) t += u;
      }
      wsum[lane] = t;
    }
    __syncthreads();
    int prev = (wv > 0) ? wsum[wv - 1] : 0;
    int excl = carry + prev + s - v;
    if (i < N_NODES) off[i] = excl;
    int total = wsum[15];
    __syncthreads();
    if (tid == 0) carry += total;
    __syncthreads();
  }
  if (tid == 0) off[N_NODES] = carry;
}

__global__ __launch_bounds__(256) void scatter_k(const int* __restrict__ ei,
                                                 const int* __restrict__ off,
                                                 int* __restrict__ cnt,
                                                 int* __restrict__ csr_src) {
  int e = blockIdx.x * 256 + threadIdx.x;
  if (e >= E_EDGES) return;
  int d = ei[E_EDGES + e];
  int pos = off[d] + atomicAdd(&cnt[d], 1);
  csr_src[pos] = ei[e];
}

// ---------------------------------------------------------------- GAT gather (1 wave / dst)
template <int RELU>
__global__ __launch_bounds__(256) void gather_k(const int* __restrict__ off,
                                                const int* __restrict__ csr_src,
                                                const float* __restrict__ es,
                                                const float* __restrict__ ed,
                                                const unsigned* __restrict__ esm,
                                                const float* __restrict__ Hg,
                                                const float* __restrict__ bias,
                                                float* __restrict__ out) {
  int wv = threadIdx.x >> 6, lane = threadIdx.x & 63;
  int d = blockIdx.x * 4 + wv;
  if (d >= N_NODES) return;
  int hd0 = lane >> 4, hd1 = 4 + (lane >> 4);
  float ed0 = ed[d * 8 + hd0], ed1 = ed[d * 8 + hd1];
  float cb0 = leaky(fdec(esm[hd0]) + ed0);
  float cb1 = leaky(fdec(esm[hd1]) + ed1);
  int e0 = off[d], e1 = off[d + 1];
  float acc0 = 0, acc1 = 0, den0 = 0, den1 = 0;
  for (int i = e0; i < e1; i++) {
    int s = csr_src[i];
    float p0 = fexp2(1.44269504f * (leaky(es[s * 8 + hd0] + ed0) - cb0));
    float p1 = fexp2(1.44269504f * (leaky(es[s * 8 + hd1] + ed1) - cb1));
    float h0 = Hg[(size_t)s * HC + lane];
    float h1 = Hg[(size_t)s * HC + 64 + lane];
    acc0 = fmaf(p0, h0, acc0); acc1 = fmaf(p1, h1, acc1);
    den0 += p0; den1 += p1;
  }
  float o0 = acc0 * frcp(den0 + 1e-16f);
  float o1 = acc1 * frcp(den1 + 1e-16f);
  if (RELU) {
    o0 = fmaxf(o0 + bias[lane], 0.f);
    o1 = fmaxf(o1 + bias[64 + lane], 0.f);
  }
  out[(size_t)d * HC + lane] = o0;
  out[(size_t)d * HC + 64 + lane] = o1;
}

// ---------------------------------------------------------------- output heads
__global__ __launch_bounds__(64) void heads_k(const float* __restrict__ xgb,
                                              const float* __restrict__ bg2,
                                              const float* __restrict__ H2,
                                              const float* __restrict__ Wc, const float* __restrict__ bc,
                                              const float* __restrict__ Wmu, const float* __restrict__ bmu,
                                              const float* __restrict__ Wm, const float* __restrict__ bm,
                                              float* __restrict__ out) {
  int n = blockIdx.x, l = threadIdx.x;
  __shared__ float xg[HC];
  __shared__ float xr[HDIM];
  for (int i = l; i < HC; i += 64) xg[i] = xgb[(size_t)n * HC + i] + bg2[i];
  for (int i = l; i < HDIM; i += 64) xr[i] = fmaxf(H2[(size_t)n * HDIM + i], 0.f);
  __syncthreads();
  float acc = bm[l];
#pragma unroll 8
  for (int k = 0; k < HC; k++) acc = fmaf(xg[k], Wm[k * MS + l], acc);
  out[N_NODES + (size_t)n * MS + l] = tanh_(acc);
  if (l < NA) {
    float a = bmu[l];
    for (int k = 0; k < HDIM; k++) a = fmaf(xr[k], Wmu[k * NA + l], a);
    for (int k = 0; k < HC; k++) a = fmaf(xg[k], Wmu[(HDIM + k) * NA + l], a);
    out[N_NODES + (size_t)N_NODES * MS + (size_t)n * NA + l] = tanh_(a);
  }
  if (l == 0) {
    float a = bc[0];
    for (int k = 0; k < HC; k++) a = fmaf(xg[k], Wc[k], a);
    out[n] = sigm(a);
  }
}

// ---------------------------------------------------------------- launch
extern "C" void kernel_launch(void* const* d_in, const int* in_sizes, int n_in,
                              void* d_out, int out_size, void* d_ws, size_t ws_size,
                              hipStream_t stream) {
  const float* state = (const float*)d_in[0];
  const float* message = (const float*)d_in[1];
  const int* ei = (const int*)d_in[2];
  const float* Wfc1 = (const float*)d_in[3]; const float* bfc1 = (const float*)d_in[4];
  const float* Wfc2 = (const float*)d_in[5]; const float* bfc2 = (const float*)d_in[6];
  const float* Wih0 = (const float*)d_in[7]; const float* Whh0 = (const float*)d_in[8];
  const float* bih0 = (const float*)d_in[9]; const float* bhh0 = (const float*)d_in[10];
  const float* Wih1 = (const float*)d_in[11]; const float* Whh1 = (const float*)d_in[12];
  const float* bih1 = (const float*)d_in[13]; const float* bhh1 = (const float*)d_in[14];
  const float* Wg1 = (const float*)d_in[15]; const float* as1 = (const float*)d_in[16];
  const float* ad1 = (const float*)d_in[17]; const float* bg1 = (const float*)d_in[18];
  const float* Wg2 = (const float*)d_in[19]; const float* as2 = (const float*)d_in[20];
  const float* ad2 = (const float*)d_in[21]; const float* bg2 = (const float*)d_in[22];
  const float* Wc = (const float*)d_in[23]; const float* bc = (const float*)d_in[24];
  const float* Wmu = (const float*)d_in[25]; const float* bmu = (const float*)d_in[26];
  const float* Wm = (const float*)d_in[27]; const float* bm = (const float*)d_in[28];

  float* ws = (float*)d_ws;
  float* GI = ws;                       // [20000 x 768]; dead after scans, region reused:
  float* HGa = ws;                      //   [20000 x 128] gat h
  float* HGb = ws + 2560000;            //   [20000 x 128] aggregation out (layer2)
  float* X2  = ws + 5120000;            //   [20000 x 128] relu(gat1+bg1)
  float* ES  = ws + 7680000;            //   [20000 x 8]
  float* ED  = ws + 7840000;            //   [20000 x 8]
  unsigned* ESM = (unsigned*)(ws + 8160000);  // [8]
  int* DEG = (int*)(ws + 8200000);      //   [20000]
  int* OFF = (int*)(ws + 8230000);      //   [20001]
  int* CNT = (int*)(ws + 8260000);      //   [20000]
  int* CSR = (int*)(ws + 8300000);      //   [640000]
  float* X  = ws + 15360000;            // [20000 x 256], reused as H1
  float* H2 = ws + 20480000;            // [20000 x 256]
  uint32_t* Wpk = (uint32_t*)(ws + 25600000); // [48*512 uint4]
  float* out = (float*)d_out;

  int rt = (N_NODES + 63) / 64;  // 313 row tiles

  gemm_k<GF_BIAS | GF_RELU_OUT><<<rt * 4, 256, 0, stream>>>(state, Wfc1, bfc1, X, N_NODES, 64, 256);
  gemm_k<GF_BIAS | GF_RELU_OUT | GF_ACC><<<rt * 4, 256, 0, stream>>>(message, Wfc2, bfc2, X, N_NODES, 64, 256);
  gemm_k<GF_BIAS | GF_BT><<<rt * 12, 256, 0, stream>>>(X, Wih0, bih0, GI, N_NODES, 256, G3);
  prep_w<<<384, 256, 0, stream>>>(Whh0, Wpk);
  gru_scan<<<1, 512, 0, stream>>>(GI, Wpk, bhh0, X);  // H1 overwrites X
  gemm_k<GF_BIAS | GF_BT><<<rt * 12, 256, 0, stream>>>(X, Wih1, bih1, GI, N_NODES, 256, G3);
  prep_w<<<384, 256, 0, stream>>>(Whh1, Wpk);
  gru_scan<<<1, 512, 0, stream>>>(GI, Wpk, bhh1, H2);
  hipMemsetAsync(DEG, 0, N_NODES * 4, stream);
  hipMemsetAsync(CNT, 0, N_NODES * 4, stream);
  deg_k<<<2500, 256, 0, stream>>>(ei, DEG);
  scan_k<<<1, 1024, 0, stream>>>(DEG, OFF);
  scatter_k<<<2500, 256, 0, stream>>>(ei, OFF, CNT, CSR);
  gemm_k<GF_RELU_A><<<rt * 2, 256, 0, stream>>>(H2, Wg1, nullptr, HGa, N_NODES, 256, HC);
  esed_k<<<625, 256, 0, stream>>>(HGa, as1, ad1, ES, ED);
  hipMemsetAsync(ESM, 0, 8 * 4, stream);
  esmax_k<<<625, 256, 0, stream>>>(ES, ESM);
  gather_k<1><<<5000, 256, 0, stream>>>(OFF, CSR, ES, ED, ESM, HGa, bg1, X2);
  gemm_k<0><<<rt * 2, 256, 0, stream>>>(X2, Wg2, nullptr, HGa, N_NODES, HC, HC);
  esed_k<<<625, 256, 0, stream>>>(HGa, as2, ad2, ES, ED);
  hipMemsetAsync(ESM, 0, 8 * 4, stream);
  esmax_k<<<625, 256, 0, stream>>>(ES, ESM);
  gather_k<0><<<5000, 256, 0, stream>>>(OFF, CSR, ES, ED, ESM, HGa, nullptr, HGb);
  heads_k<<<N_NODES, 64, 0, stream>>>(HGb, bg2, H2, Wc, bc, Wmu, bmu, Wm, bm, out);
}